// Round 6
// baseline (143.065 us; speedup 1.0000x reference)
//
#include <hip/hip_runtime.h>

// Compact bilinear pooling via Gram GEMM + hash scatter (no FFT).
//   out[b, (h1[c1]+h2[c2]) % D] += s1[c1]*s2[c2] * G[b,c1,c2],
//   G[b] = X1_b^T X2_b over HW=196 pixels.
//
// R6: attack the real floor found in R5 (fragment-load latency serialization:
// 416 scalar dword loads/thread, k-stride 2KB, un-pipelineable). New fast
// path: (1) transpose+convert x -> bf16 xT[b][c][kp], kp padded 196->224
// (14 full K=16 MFMA steps, no tail); (2) Gram fragments load k-contiguous
// 16B dwordx4 (56 VMEM instrs/thread, 7.4x fewer, zero per-step cvt);
// (3) proven LDS-bucket scatter + ws partials + reduce.

#define NB   32
#define HW   196
#define CC   512
#define DD   8192
#define KP   224
#define NTHR 256
#define TILES_PER_B 16

typedef __attribute__((ext_vector_type(8)))  __bf16 bf8;
typedef __attribute__((ext_vector_type(16))) float  f32x16;

#define XT_ELEMS ((size_t)NB * CC * KP)                  // 3,670,016 bf16
#define XT_BYTES (XT_ELEMS * 2)                          // 7,340,032 B
#define PART_OFF_BYTES (2 * XT_BYTES)                    // 14,680,064 B
#define PART_BYTES ((size_t)NB * TILES_PER_B * DD * 4)   // 16,777,216 B
#define NEED_FAST (PART_OFF_BYTES + PART_BYTES)          // 31,457,280 B
#define NEED_R5  PART_BYTES

// ---------- pass 1: x[b][k][c] fp32 -> xT[b][c][kp] bf16 (kp zero-padded) ----
__global__ __launch_bounds__(NTHR) void cbp_transpose_kernel(
    const float* __restrict__ x1, const float* __restrict__ x2,
    __bf16* __restrict__ xT1, __bf16* __restrict__ xT2)
{
    __shared__ float T[64][65];
    const int bid = blockIdx.x;          // b*32 + ct*4 + kt
    const int b  = bid >> 5;
    const int ct = (bid >> 2) & 7;       // c tile (8 x 64)
    const int kt = bid & 3;              // k tile (4 x 64, covers kp<256)
    const int tid = threadIdx.x;

    #pragma unroll
    for (int m = 0; m < 2; ++m) {
        const float* x   = m ? x2  : x1;
        __bf16*      xTo = m ? xT2 : xT1;

        // stage 64k x 64c fp32 tile (coalesced float4 rows), zero-pad k>=196
        #pragma unroll
        for (int p = 0; p < 4; ++p) {
            const int row  = p * 16 + (tid >> 4);      // k_local
            const int col4 = (tid & 15) * 4;           // c_local
            const int k = kt * 64 + row;
            float4 v = {0.f, 0.f, 0.f, 0.f};
            if (k < HW)
                v = *(const float4*)(x + ((size_t)(b * HW + k) * CC + ct * 64 + col4));
            T[col4 + 0][row] = v.x;
            T[col4 + 1][row] = v.y;
            T[col4 + 2][row] = v.z;
            T[col4 + 3][row] = v.w;
        }
        __syncthreads();

        // write out rows of xT: 64 c-rows x 64 kp, bf16, 16B stores
        const int c_l = tid >> 2;        // 0..63
        const int seg = tid & 3;         // 16 kp per seg
        const int kp0 = kt * 64 + seg * 16;
        if (kp0 < KP) {
            const size_t dstc = (size_t)(b * CC + ct * 64 + c_l) * KP;
            #pragma unroll
            for (int i2 = 0; i2 < 2; ++i2) {
                bf8 v;
                #pragma unroll
                for (int i = 0; i < 8; ++i)
                    v[i] = (__bf16)T[c_l][seg * 16 + i2 * 8 + i];
                *(bf8*)(xTo + dstc + kp0 + i2 * 8) = v;
            }
        }
        __syncthreads();
    }
}

// ---------- pass 2: Gram MFMA + hash scatter -> per-block partials ----------
__global__ __launch_bounds__(NTHR) void cbp_gram_t_kernel(
    const __bf16* __restrict__ xT1, const __bf16* __restrict__ xT2,
    const float* __restrict__ s1, const float* __restrict__ s2,
    const int*   __restrict__ h1, const int*   __restrict__ h2,
    float* __restrict__ partials)
{
    __shared__ float accD[DD];

    const int bid  = blockIdx.x;
    const int b    = bid >> 4;
    const int t1   = (bid >> 2) & 3;
    const int t2   = bid & 3;
    const int tid  = threadIdx.x;
    const int wid  = tid >> 6;
    const int lane = tid & 63;
    const int wr   = wid >> 1;
    const int wc   = wid & 1;
    const int lo5  = lane & 31;
    const int hi   = lane >> 5;

    for (int i = tid; i < DD; i += NTHR) accD[i] = 0.0f;
    __syncthreads();

    const int c1w = t1 * 128 + wr * 64;
    const int c2w = t2 * 128 + wc * 64;

    // k-contiguous bf16 fragment bases: lane = column, 16B = 8 k per load
    const __bf16* A0 = xT1 + ((size_t)(b * CC + c1w + lo5) * KP + hi * 8);
    const __bf16* A1 = A0 + (size_t)32 * KP;
    const __bf16* B0 = xT2 + ((size_t)(b * CC + c2w + lo5) * KP + hi * 8);
    const __bf16* B1 = B0 + (size_t)32 * KP;

    f32x16 acc00 = {}, acc01 = {}, acc10 = {}, acc11 = {};

    #pragma unroll
    for (int ks = 0; ks < KP / 16; ++ks) {      // 14 steps, no tail
        const bf8 a0  = *(const bf8*)(A0 + ks * 16);
        const bf8 a1  = *(const bf8*)(A1 + ks * 16);
        const bf8 b0v = *(const bf8*)(B0 + ks * 16);
        const bf8 b1v = *(const bf8*)(B1 + ks * 16);
        acc00 = __builtin_amdgcn_mfma_f32_32x32x16_bf16(a0, b0v, acc00, 0, 0, 0);
        acc01 = __builtin_amdgcn_mfma_f32_32x32x16_bf16(a0, b1v, acc01, 0, 0, 0);
        acc10 = __builtin_amdgcn_mfma_f32_32x32x16_bf16(a1, b0v, acc10, 0, 0, 0);
        acc11 = __builtin_amdgcn_mfma_f32_32x32x16_bf16(a1, b1v, acc11, 0, 0, 0);
    }

    // scatter into LDS buckets. C/D layout: col=lane&31, row=(reg&3)+8*(reg>>2)+4*hi
    const float s2v0 = s2[c2w + lo5];
    const float s2v1 = s2[c2w + 32 + lo5];
    const int   h2v0 = h2[c2w + lo5];
    const int   h2v1 = h2[c2w + 32 + lo5];

    #pragma unroll
    for (int rt = 0; rt < 2; ++rt) {
        const f32x16 accL = rt ? acc10 : acc00;
        const f32x16 accR = rt ? acc11 : acc01;
        #pragma unroll
        for (int reg = 0; reg < 16; ++reg) {
            const int c1 = c1w + rt * 32 + (reg & 3) + 8 * (reg >> 2) + 4 * hi;
            const float sv = s1[c1];
            const int   hv = h1[c1];
            atomicAdd(&accD[(hv + h2v0) & (DD - 1)], sv * s2v0 * accL[reg]);
            atomicAdd(&accD[(hv + h2v1) & (DD - 1)], sv * s2v1 * accR[reg]);
        }
    }
    __syncthreads();

    float4* dst = (float4*)(partials + (size_t)bid * DD);
    const float4* src = (const float4*)accD;
    #pragma unroll
    for (int i = 0; i < DD / 4 / NTHR; ++i)
        dst[tid + i * NTHR] = src[tid + i * NTHR];
}

// ---------- R5 fallback: Gram from fp32 with scalar loads ----------
__global__ __launch_bounds__(NTHR) void cbp_mfma_kernel(
    const float* __restrict__ x1, const float* __restrict__ x2,
    const float* __restrict__ s1, const float* __restrict__ s2,
    const int*   __restrict__ h1, const int*   __restrict__ h2,
    float* __restrict__ ws, float* __restrict__ out, int use_ws)
{
    __shared__ float accD[DD];
    const int bid  = blockIdx.x;
    const int b    = bid >> 4;
    const int t1   = (bid >> 2) & 3;
    const int t2   = bid & 3;
    const int tid  = threadIdx.x;
    const int wid  = tid >> 6;
    const int lane = tid & 63;
    const int wr   = wid >> 1;
    const int wc   = wid & 1;
    const int lo5  = lane & 31;
    const int hi   = lane >> 5;

    for (int i = tid; i < DD; i += NTHR) accD[i] = 0.0f;
    __syncthreads();

    const int c1w = t1 * 128 + wr * 64;
    const int c2w = t2 * 128 + wc * 64;
    const float* A0 = x1 + (size_t)b * HW * CC + (c1w + lo5);
    const float* A1 = A0 + 32;
    const float* B0 = x2 + (size_t)b * HW * CC + (c2w + lo5);
    const float* B1 = B0 + 32;

    f32x16 acc00 = {}, acc01 = {}, acc10 = {}, acc11 = {};
    for (int ks = 0; ks < 12; ++ks) {
        const int kb = ks * 16 + hi * 8;
        bf8 a0, a1, b0v, b1v;
        #pragma unroll
        for (int j = 0; j < 8; ++j) {
            const size_t off = (size_t)(kb + j) * CC;
            a0[j] = (__bf16)A0[off]; a1[j] = (__bf16)A1[off];
            b0v[j] = (__bf16)B0[off]; b1v[j] = (__bf16)B1[off];
        }
        acc00 = __builtin_amdgcn_mfma_f32_32x32x16_bf16(a0, b0v, acc00, 0, 0, 0);
        acc01 = __builtin_amdgcn_mfma_f32_32x32x16_bf16(a0, b1v, acc01, 0, 0, 0);
        acc10 = __builtin_amdgcn_mfma_f32_32x32x16_bf16(a1, b0v, acc10, 0, 0, 0);
        acc11 = __builtin_amdgcn_mfma_f32_32x32x16_bf16(a1, b1v, acc11, 0, 0, 0);
    }
    {
        const int kb = 192 + hi * 8;
        bf8 a0, a1, b0v, b1v;
        #pragma unroll
        for (int j = 0; j < 8; ++j) {
            const int k = kb + j;
            const size_t off = (size_t)k * CC;
            const bool v = (k < HW);
            a0[j]  = (__bf16)(v ? A0[off] : 0.0f);
            a1[j]  = (__bf16)(v ? A1[off] : 0.0f);
            b0v[j] = (__bf16)(v ? B0[off] : 0.0f);
            b1v[j] = (__bf16)(v ? B1[off] : 0.0f);
        }
        acc00 = __builtin_amdgcn_mfma_f32_32x32x16_bf16(a0, b0v, acc00, 0, 0, 0);
        acc01 = __builtin_amdgcn_mfma_f32_32x32x16_bf16(a0, b1v, acc01, 0, 0, 0);
        acc10 = __builtin_amdgcn_mfma_f32_32x32x16_bf16(a1, b0v, acc10, 0, 0, 0);
        acc11 = __builtin_amdgcn_mfma_f32_32x32x16_bf16(a1, b1v, acc11, 0, 0, 0);
    }

    const float s2v0 = s2[c2w + lo5];
    const float s2v1 = s2[c2w + 32 + lo5];
    const int   h2v0 = h2[c2w + lo5];
    const int   h2v1 = h2[c2w + 32 + lo5];
    #pragma unroll
    for (int rt = 0; rt < 2; ++rt) {
        const f32x16 accL = rt ? acc10 : acc00;
        const f32x16 accR = rt ? acc11 : acc01;
        #pragma unroll
        for (int reg = 0; reg < 16; ++reg) {
            const int c1 = c1w + rt * 32 + (reg & 3) + 8 * (reg >> 2) + 4 * hi;
            const float sv = s1[c1];
            const int   hv = h1[c1];
            atomicAdd(&accD[(hv + h2v0) & (DD - 1)], sv * s2v0 * accL[reg]);
            atomicAdd(&accD[(hv + h2v1) & (DD - 1)], sv * s2v1 * accR[reg]);
        }
    }
    __syncthreads();

    if (use_ws) {
        float4* dst = (float4*)(ws + (size_t)bid * DD);
        const float4* src = (const float4*)accD;
        #pragma unroll
        for (int i = 0; i < DD / 4 / NTHR; ++i)
            dst[tid + i * NTHR] = src[tid + i * NTHR];
    } else {
        float* ob = out + (size_t)b * DD;
        for (int i = tid; i < DD; i += NTHR)
            atomicAdd(&ob[i], accD[i]);
    }
}

// ---------- pass 3: reduce 16 partials per (b,d) ----------
__global__ __launch_bounds__(NTHR) void cbp_reduce_kernel(
    const float* __restrict__ parts, float* __restrict__ out)
{
    const int b  = blockIdx.x >> 3;
    const int d0 = (blockIdx.x & 7) * 1024 + threadIdx.x * 4;
    const float* base = parts + (size_t)b * TILES_PER_B * DD + d0;
    float4 sum = {0.f, 0.f, 0.f, 0.f};
    #pragma unroll
    for (int t = 0; t < TILES_PER_B; ++t) {
        float4 v = *(const float4*)(base + (size_t)t * DD);
        sum.x += v.x; sum.y += v.y; sum.z += v.z; sum.w += v.w;
    }
    *(float4*)(out + (size_t)b * DD + d0) = sum;
}

extern "C" void kernel_launch(void* const* d_in, const int* in_sizes, int n_in,
                              void* d_out, int out_size, void* d_ws, size_t ws_size,
                              hipStream_t stream) {
    const float* x1 = (const float*)d_in[0];
    const float* x2 = (const float*)d_in[1];
    const float* s1 = (const float*)d_in[2];
    const float* s2 = (const float*)d_in[3];
    const int*   h1 = (const int*)d_in[4];
    const int*   h2 = (const int*)d_in[5];
    float* out = (float*)d_out;

    dim3 block(NTHR);
    if (ws_size >= NEED_FAST) {
        __bf16* xT1 = (__bf16*)d_ws;
        __bf16* xT2 = xT1 + XT_ELEMS;
        float*  parts = (float*)((char*)d_ws + PART_OFF_BYTES);
        cbp_transpose_kernel<<<dim3(NB * 32), block, 0, stream>>>(x1, x2, xT1, xT2);
        cbp_gram_t_kernel<<<dim3(NB * TILES_PER_B), block, 0, stream>>>(
            xT1, xT2, s1, s2, h1, h2, parts);
        cbp_reduce_kernel<<<dim3(NB * 8), block, 0, stream>>>(parts, out);
    } else if (ws_size >= NEED_R5) {
        float* parts = (float*)d_ws;
        cbp_mfma_kernel<<<dim3(NB * TILES_PER_B), block, 0, stream>>>(
            x1, x2, s1, s2, h1, h2, parts, out, 1);
        cbp_reduce_kernel<<<dim3(NB * 8), block, 0, stream>>>(parts, out);
    } else {
        hipMemsetAsync(out, 0, (size_t)out_size * sizeof(float), stream);
        cbp_mfma_kernel<<<dim3(NB * TILES_PER_B), block, 0, stream>>>(
            x1, x2, s1, s2, h1, h2, (float*)d_ws, out, 0);
    }
}